// Round 10
// baseline (179.488 us; speedup 1.0000x reference)
//
#include <hip/hip_runtime.h>
#include <hip/hip_bf16.h>
#include <cstdint>

// Problem constants (MSA: B=8, N=1024, E=768, H=12, D=64)
#define BATCH 8
#define SEQ   1024
#define EMB   768
#define HEADS 12
#define HDIM  64
#define C3    2304          // 3*EMB
#define MROWS (BATCH*SEQ)   // 8192
#define KSLC  (EMB / 16)    // 48 k-slices
#define XPACK_BLOCKS (MROWS * KSLC / 256)   // 1536
#define WPACK_BLOCKS (C3 * KSLC / 256)      // 432

typedef __attribute__((ext_vector_type(8)))  short bf16x8;
typedef __attribute__((ext_vector_type(4)))  short bf16x4;
typedef __attribute__((ext_vector_type(4)))  float f32x4;
typedef __attribute__((ext_vector_type(16))) float f32x16;

// fp32 -> bf16 round-to-nearest-even
static __device__ inline short f2bf(float f) {
    union { float f; uint32_t u; } v; v.f = f;
    uint32_t u = v.u + 0x7fff + ((v.u >> 16) & 1);
    return (short)(u >> 16);
}

// ---------------------------------------------------------------------------
// Kernel 0 (round-9, unchanged): fp32 -> bf16 convert + pack into MFMA
// fragment order for BOTH x and W. Chunk(tile,ks) = 512 shorts = 32r x 16k.
// ---------------------------------------------------------------------------
__global__ __launch_bounds__(256) void pack_bf16(const float* __restrict__ x,
                                                 short* __restrict__ xb2,
                                                 const float* __restrict__ W,
                                                 short* __restrict__ Wb2) {
    const float* in;
    short* out;
    int tid;
    if (blockIdx.x < XPACK_BLOCKS) {
        in = x; out = xb2;
        tid = blockIdx.x * 256 + threadIdx.x;
    } else {
        in = W; out = Wb2;
        tid = (blockIdx.x - XPACK_BLOCKS) * 256 + threadIdx.x;
    }
    const int r    = tid & 31;
    const int ks   = (tid >> 5) % KSLC;
    const int tile = tid / (KSLC * 32);
    const int row  = tile * 32 + r;

    const float* src = in + (size_t)row * EMB + ks * 16;
    float4 v0 = ((const float4*)src)[0];
    float4 v1 = ((const float4*)src)[1];
    float4 v2 = ((const float4*)src)[2];
    float4 v3 = ((const float4*)src)[3];
    bf16x8 o0 = { f2bf(v0.x), f2bf(v0.y), f2bf(v0.z), f2bf(v0.w),
                  f2bf(v1.x), f2bf(v1.y), f2bf(v1.z), f2bf(v1.w) };
    bf16x8 o1 = { f2bf(v2.x), f2bf(v2.y), f2bf(v2.z), f2bf(v2.w),
                  f2bf(v3.x), f2bf(v3.y), f2bf(v3.z), f2bf(v3.w) };
    short* dst = out + (size_t)tid * 16;
    *(bf16x8*)(dst)     = o0;
    *(bf16x8*)(dst + 8) = o1;
}

// ---------------------------------------------------------------------------
// Kernel 1 (RESTRUCTURED EPILOGUE): LDS-free barrier-free bf16 MFMA GEMM
// + XCD swizzle + head-layout split outputs:
//   Q -> qb[(b*12+h)*1024 + i][d]   (x 1/8 scale folded)
//   K -> kb[(b*12+h)*1024 + j][d]
//   V -> vt[(b*12+h)*64 + d][j]     (TRANSPOSED in the epilogue; runs of 4
//                                    consecutive j per store, L2 merges)
// Every 32-col nt sub-tile lies wholly in one (head, component) 64-block,
// so routing is wave-uniform per nt.
// ---------------------------------------------------------------------------
__global__ __launch_bounds__(256) void qkv_gemm_mfma(const short* __restrict__ xb2,
                                                     const short* __restrict__ Wb2,
                                                     const float* __restrict__ bias,
                                                     short* __restrict__ qb,
                                                     short* __restrict__ kb,
                                                     short* __restrict__ vt) {
    const int g    = blockIdx.x;         // 0..1151
    const int xcd  = g & 7;
    const int ring = g >> 3;             // 0..143
    const int by   = xcd * 8 + (ring & 7);   // M-tile 0..63
    const int bx   = ring >> 3;              // N-tile 0..17

    const int t = threadIdx.x;
    const int w = t >> 6;
    const int lane = t & 63;
    const int l5  = lane >> 5;
    const int r31 = lane & 31;
    const int m0 = by * 128, n0 = bx * 128;
    const int wm = (w & 1) * 64, wn = (w >> 1) * 64;

    const int laneoff = r31 * 16 + l5 * 8;
    const short* pa0 = xb2 + ((size_t)((m0 + wm) >> 5) * KSLC) * 512 + laneoff;
    const short* pa1 = pa0 + (size_t)KSLC * 512;
    const short* pb0 = Wb2 + ((size_t)((n0 + wn) >> 5) * KSLC) * 512 + laneoff;
    const short* pb1 = pb0 + (size_t)KSLC * 512;

    f32x16 acc[2][2] = {};

    #pragma unroll 4
    for (int ks = 0; ks < KSLC; ++ks) {
        bf16x8 a0 = *(const bf16x8*)(pa0 + ks * 512);
        bf16x8 a1 = *(const bf16x8*)(pa1 + ks * 512);
        bf16x8 b0 = *(const bf16x8*)(pb0 + ks * 512);
        bf16x8 b1 = *(const bf16x8*)(pb1 + ks * 512);
        acc[0][0] = __builtin_amdgcn_mfma_f32_32x32x16_bf16(a0, b0, acc[0][0], 0, 0, 0);
        acc[0][1] = __builtin_amdgcn_mfma_f32_32x32x16_bf16(a0, b1, acc[0][1], 0, 0, 0);
        acc[1][0] = __builtin_amdgcn_mfma_f32_32x32x16_bf16(a1, b0, acc[1][0], 0, 0, 0);
        acc[1][1] = __builtin_amdgcn_mfma_f32_32x32x16_bf16(a1, b1, acc[1][1], 0, 0, 0);
    }

    // ---- epilogue: route each nt sub-tile to qb / kb / vt ----
    const int b  = m0 >> 10;             // batch index (uniform per block)
    const int mi = (m0 & 1023) + wm;     // i-base within sequence
    #pragma unroll
    for (int nt = 0; nt < 2; ++nt) {
        const int n_start = n0 + wn + nt * 32;       // uniform
        const int h    = n_start / 192;
        const int comp = (n_start % 192) >> 6;       // 0=Q, 1=K, 2=V
        const int d    = (n_start & 63) + r31;       // lane channel in [0,64)
        const float bv = bias[n_start + r31];
        const float sc = (comp == 0) ? 0.125f : 1.0f;
        const size_t bh = (size_t)(b * HEADS + h);

        if (comp < 2) {
            short* dst = (comp == 0 ? qb : kb) + bh * SEQ * 64 + d;
            #pragma unroll
            for (int mt = 0; mt < 2; ++mt)
                #pragma unroll
                for (int reg = 0; reg < 16; ++reg) {
                    int row = (reg & 3) + 8 * (reg >> 2) + 4 * l5;
                    int i = mi + mt * 32 + row;
                    dst[(size_t)i * 64] = f2bf((acc[mt][nt][reg] + bv) * sc);
                }
        } else {
            short* dst = vt + (bh * 64 + d) * SEQ;
            #pragma unroll
            for (int mt = 0; mt < 2; ++mt)
                #pragma unroll
                for (int gr = 0; gr < 4; ++gr) {
                    int j0r = mi + mt * 32 + 8 * gr + 4 * l5;
                    bf16x4 pv = { f2bf(acc[mt][nt][4 * gr + 0] + bv),
                                  f2bf(acc[mt][nt][4 * gr + 1] + bv),
                                  f2bf(acc[mt][nt][4 * gr + 2] + bv),
                                  f2bf(acc[mt][nt][4 * gr + 3] + bv) };
                    *(bf16x4*)(dst + j0r) = pv;
                }
        }
    }
}

// ---------------------------------------------------------------------------
// Kernel 2: 128-query-tile flash attention (round-8/9 structure) with
// head-contiguous inputs: Q/K staging now fully dense (1 KB contiguous per
// wave instruction). XCD swizzle: qt is the slow grid index.
// ---------------------------------------------------------------------------
#define LDP 72   // LDS row stride in bf16 elems: 64 + 8 pad

__global__ __launch_bounds__(256, 3) void attn_mfma(const short* __restrict__ qb,
                                                    const short* __restrict__ kb,
                                                    const short* __restrict__ vt,
                                                    float* __restrict__ out) {
    __shared__ short Ks[64][LDP];    // 9.2 KB
    __shared__ short Vt[64][LDP];    // 9.2 KB   Vt[d][j]
    __shared__ short Ps[128][LDP];   // 18.4 KB  Q staging, then P strips

    const int g    = blockIdx.x;              // 0..767
    const int qt   = g / (BATCH * HEADS);     // 0..7  (slow index)
    const int bh   = g % (BATCH * HEADS);
    const int b    = bh / HEADS;
    const int h    = bh % HEADS;
    const int t    = threadIdx.x;
    const int w    = t >> 6;
    const int lane = t & 63;
    const int c    = lane & 15;
    const int q    = lane >> 4;
    const int i0   = qt * 128;

    const short* qbb = qb + (size_t)bh * SEQ * 64;
    const short* kbb = kb + (size_t)bh * SEQ * 64;
    const short* vtb = vt + (size_t)bh * 64 * SEQ;

    // ---- stage Q tile (128 rows, pre-scaled by 1/8): dense copy ----
    #pragma unroll
    for (int p = 0; p < 4; ++p) {
        int idx = p * 256 + t;
        int i = idx >> 3, d0 = (idx & 7) << 3;
        *(bf16x8*)&Ps[i][d0] = *(const bf16x8*)(qbb + (size_t)i0 * 64 + idx * 8);
    }
    __syncthreads();
    bf16x8 aq[2][2];
    #pragma unroll
    for (int s = 0; s < 2; ++s) {
        aq[s][0] = *(bf16x8*)&Ps[w * 32 + s * 16 + c][q * 8];
        aq[s][1] = *(bf16x8*)&Ps[w * 32 + s * 16 + c][32 + q * 8];
    }

    f32x4 o[2][4] = {};
    float l_acc[2] = {0.f, 0.f};

    for (int kt = 0; kt < 16; ++kt) {
        const int j0 = kt * 64;
        __syncthreads();   // prev tile's K/V frag reads done
        // ---- stage K tile: dense copy ----
        #pragma unroll
        for (int p = 0; p < 2; ++p) {
            int idx = p * 256 + t;
            int j = idx >> 3, d0 = (idx & 7) << 3;
            *(bf16x8*)&Ks[j][d0] = *(const bf16x8*)(kbb + (size_t)j0 * 64 + idx * 8);
        }
        // ---- stage V^T tile ----
        #pragma unroll
        for (int p = 0; p < 2; ++p) {
            int idx = p * 256 + t;
            int d = idx >> 3, j8 = (idx & 7) << 3;
            *(bf16x8*)&Vt[d][j8] =
                *(const bf16x8*)(vtb + (size_t)d * SEQ + j0 + j8);
        }
        __syncthreads();

        // ---- K fragments once, shared by both q-sub-tiles ----
        bf16x8 ka[4][2];
        #pragma unroll
        for (int mt = 0; mt < 4; ++mt) {
            ka[mt][0] = *(bf16x8*)&Ks[mt * 16 + c][q * 8];
            ka[mt][1] = *(bf16x8*)&Ks[mt * 16 + c][32 + q * 8];
        }

        // ---- S^T = K Q^T for both sub-tiles ----
        f32x4 s[2][4];
        #pragma unroll
        for (int ss = 0; ss < 2; ++ss)
            #pragma unroll
            for (int mt = 0; mt < 4; ++mt) {
                f32x4 acc = {0.f, 0.f, 0.f, 0.f};
                acc = __builtin_amdgcn_mfma_f32_16x16x32_bf16(ka[mt][0], aq[ss][0], acc, 0, 0, 0);
                acc = __builtin_amdgcn_mfma_f32_16x16x32_bf16(ka[mt][1], aq[ss][1], acc, 0, 0, 0);
                s[ss][mt] = acc;
            }

        // ---- exp (no max), accumulate l, pack P as b64 writes ----
        #pragma unroll
        for (int ss = 0; ss < 2; ++ss)
            #pragma unroll
            for (int mt = 0; mt < 4; ++mt) {
                float p0 = __expf(s[ss][mt][0]);
                float p1 = __expf(s[ss][mt][1]);
                float p2 = __expf(s[ss][mt][2]);
                float p3 = __expf(s[ss][mt][3]);
                l_acc[ss] += (p0 + p1) + (p2 + p3);
                bf16x4 pw = { f2bf(p0), f2bf(p1), f2bf(p2), f2bf(p3) };
                *(bf16x4*)&Ps[w * 32 + ss * 16 + c][mt * 16 + 4 * q] = pw;
            }

        // ---- V fragments once, shared by both q-sub-tiles ----
        bf16x8 vb[4][2];
        #pragma unroll
        for (int dt = 0; dt < 4; ++dt) {
            vb[dt][0] = *(bf16x8*)&Vt[dt * 16 + c][q * 8];
            vb[dt][1] = *(bf16x8*)&Vt[dt * 16 + c][32 + q * 8];
        }

        // ---- O += P V ----
        #pragma unroll
        for (int ss = 0; ss < 2; ++ss) {
            bf16x8 ap0 = *(bf16x8*)&Ps[w * 32 + ss * 16 + c][q * 8];
            bf16x8 ap1 = *(bf16x8*)&Ps[w * 32 + ss * 16 + c][32 + q * 8];
            #pragma unroll
            for (int dt = 0; dt < 4; ++dt) {
                o[ss][dt] = __builtin_amdgcn_mfma_f32_16x16x32_bf16(ap0, vb[dt][0], o[ss][dt], 0, 0, 0);
                o[ss][dt] = __builtin_amdgcn_mfma_f32_16x16x32_bf16(ap1, vb[dt][1], o[ss][dt], 0, 0, 0);
            }
        }
    }

    // ---- final l reduction + redistribute to C-layout rows ----
    float linv[2][4];
    #pragma unroll
    for (int ss = 0; ss < 2; ++ss) {
        float v = l_acc[ss];
        v += __shfl_xor(v, 16, 64);
        v += __shfl_xor(v, 32, 64);
        #pragma unroll
        for (int r = 0; r < 4; ++r)
            linv[ss][r] = 1.0f / __shfl(v, 4 * q + r, 64);
    }

    // ---- epilogue: row i = w*32 + ss*16 + q*4 + r, col = 16dt + c ----
    #pragma unroll
    for (int ss = 0; ss < 2; ++ss)
        #pragma unroll
        for (int dt = 0; dt < 4; ++dt)
            #pragma unroll
            for (int r = 0; r < 4; ++r) {
                int i = w * 32 + ss * 16 + q * 4 + r;
                out[((size_t)b * SEQ + i0 + i) * EMB + h * HDIM + dt * 16 + c]
                    = o[ss][dt][r] * linv[ss][r];
            }
}

// ---------------------------------------------------------------------------
extern "C" void kernel_launch(void* const* d_in, const int* in_sizes, int n_in,
                              void* d_out, int out_size, void* d_ws, size_t ws_size,
                              hipStream_t stream) {
    const float* x    = (const float*)d_in[0];   // (8,1024,768) fp32
    const float* W    = (const float*)d_in[1];   // (2304,768)   fp32
    const float* bias = (const float*)d_in[2];   // (2304,)      fp32
    float* out = (float*)d_out;

    short* xb2 = (short*)d_ws;                        // 8192*768  bf16 (packed)
    short* Wb2 = xb2 + (size_t)MROWS * EMB;           // 2304*768  bf16 (packed)
    short* qb  = Wb2 + (size_t)C3 * EMB;              // 96*1024*64 bf16
    short* kb  = qb  + (size_t)BATCH * HEADS * SEQ * HDIM;
    short* vt  = kb  + (size_t)BATCH * HEADS * SEQ * HDIM;

    pack_bf16<<<XPACK_BLOCKS + WPACK_BLOCKS, 256, 0, stream>>>(x, xb2, W, Wb2);

    qkv_gemm_mfma<<<1152, 256, 0, stream>>>(xb2, Wb2, bias, qb, kb, vt);

    attn_mfma<<<BATCH * HEADS * (SEQ / 128), 256, 0, stream>>>(qb, kb, vt, out);
}